// Round 2
// baseline (249.129 us; speedup 1.0000x reference)
//
#include <hip/hip_runtime.h>

// Problem constants (from reference)
#define NS     4096                 // N_SAMPLES
#define NW     64                   // N_WIDTH
#define NNODES 257                  // N_NODES
#define SW     (NS * NW)            // 262144
#define ROW    (NW * NNODES)        // 16448 floats per sample region
#define ROW4   (ROW / 4)            // 4112 float4 groups per sample region
#define SWN    ((size_t)NS * NW * NNODES)  // 67,371,008

// ---------------------------------------------------------------------------
// Basis evaluation (identical arithmetic to the passing R1 kernel; derivative
// scales folded in: dphi *= 128 (1/delta_x), ddphi *= 16384 (1/delta_x^2)).
// ---------------------------------------------------------------------------
__device__ __forceinline__ void basis_eval(float xt, float* phi, float* dphi, float* ddphi)
{
    const float nd[5] = {-1.0f, -0.5f, 0.0f, 0.5f, 1.0f};
    #pragma unroll
    for (int j = 0; j < 5; ++j) {
        // phi
        float p = 1.0f;
        #pragma unroll
        for (int m = 0; m < 5; ++m)
            if (m != j) p = p * (xt - nd[m]) / (nd[j] - nd[m]);
        phi[j] = p;
        // dphi
        float y1 = 0.0f;
        #pragma unroll
        for (int ii = 0; ii < 5; ++ii) {
            if (ii != j) {
                float k = 1.0f / (nd[j] - nd[ii]);
                #pragma unroll
                for (int m = 0; m < 5; ++m)
                    if (m != ii && m != j) k = k * (xt - nd[m]) / (nd[j] - nd[m]);
                y1 += k;
            }
        }
        dphi[j] = y1 * 128.0f;
        // ddphi
        float y2 = 0.0f;
        #pragma unroll
        for (int ii = 0; ii < 5; ++ii) {
            if (ii != j) {
                float ks = 0.0f;
                #pragma unroll
                for (int m = 0; m < 5; ++m) {
                    if (m != ii && m != j) {
                        float kp = 1.0f / (nd[j] - nd[m]);
                        #pragma unroll
                        for (int n = 0; n < 5; ++n)
                            if (n != ii && n != j && n != m)
                                kp = kp * (xt - nd[n]) / (nd[j] - nd[n]);
                        ks += kp;
                    }
                }
                y2 += ks / (nd[j] - nd[ii]);
            }
        }
        ddphi[j] = y2 * 16384.0f;
    }
}

__device__ __forceinline__ int sample_base_xt(float xi, float* xt_out)
{
    const float x_shift = 256.0f * xi;
    float fel = floorf(x_shift * 0.25f);
    fel = fminf(fmaxf(fel, 0.0f), 63.0f);
    const int base = (int)fel * 4;
    *xt_out = 0.5f * (x_shift - (float)base) - 1.0f;
    return base;
}

// ---------------------------------------------------------------------------
// K1: per-sample basis table -> ws[i*16 + {phi[5], dphi[5], ddphi[5], base}]
// ---------------------------------------------------------------------------
__global__ __launch_bounds__(256) void k_basis(
    const float* __restrict__ x, float* __restrict__ ws)
{
    const int i = blockIdx.x * 256 + threadIdx.x;
    if (i >= NS) return;
    float xt;
    const int base = sample_base_xt(x[i], &xt);
    float phi[5], dphi[5], ddphi[5];
    basis_eval(xt, phi, dphi, ddphi);
    float* t = ws + (size_t)i * 16;
    #pragma unroll
    for (int j = 0; j < 5; ++j) {
        t[j]      = phi[j];
        t[5 + j]  = dphi[j];
        t[10 + j] = ddphi[j];
    }
    t[15] = (float)base;   // base <= 252, exact in fp32
}

// ---------------------------------------------------------------------------
// K2: t/dt/ddt dot products + delta_x. One wave per sample, lane = width k.
// ---------------------------------------------------------------------------
__global__ __launch_bounds__(256) void k_dots(
    const float* __restrict__ ws, const float* __restrict__ weight,
    float* __restrict__ out)
{
    const int tid  = threadIdx.x;
    const int w    = tid >> 6;
    const int lane = tid & 63;
    const int i    = blockIdx.x * 4 + w;

    const float* tb = ws + (size_t)i * 16;
    const int b = (int)tb[15];
    const float* wrow = weight + lane * NNODES + b;

    float t = 0.0f, dt = 0.0f, ddt = 0.0f;
    #pragma unroll
    for (int j = 0; j < 5; ++j) {
        const float wv = wrow[j];
        t   += wv * tb[j];
        dt  += wv * tb[5 + j];
        ddt += wv * tb[10 + j];
    }
    out[(size_t)i * NW + lane]              = t;
    out[SW + (size_t)i * NW + lane]         = dt;
    out[2 * (size_t)SW + (size_t)i * NW + lane] = ddt;

    if (blockIdx.x == 0 && tid == 0)
        out[3 * (size_t)SW + 3 * SWN] = 0.0078125f;   // delta_x
}

// ---------------------------------------------------------------------------
// K3: dominant writer. grid = (4096 samples, 3 arrays). Per block:
//   pass A (threads 0..127): write the exactly-2 affected float4 groups per
//           row as FULL float4s (value + surrounding zeros).
//   pass B (all threads): zero-fill every other float4 group (skip test).
// Disjoint addresses -> no barrier, no RMW, no partial rewrites.
// ---------------------------------------------------------------------------
__global__ __launch_bounds__(256) void k_fill(
    const float* __restrict__ ws, float* __restrict__ out)
{
    const int i   = blockIdx.x;     // sample
    const int a   = blockIdx.y;     // which array (phi/dphi/ddphi)
    const int tid = threadIdx.x;

    const float* tb = ws + (size_t)i * 16;
    const float v0 = tb[a * 5 + 0];
    const float v1 = tb[a * 5 + 1];
    const float v2 = tb[a * 5 + 2];
    const float v3 = tb[a * 5 + 3];
    const float v4 = tb[a * 5 + 4];
    const int   b  = (int)tb[15];

    float4* reg = reinterpret_cast<float4*>(
        out + 3 * (size_t)SW + (size_t)a * SWN + (size_t)i * ROW);

    // ---- pass A: affected groups (2 per row, 128 total) ----
    if (tid < 128) {
        const int k = tid >> 1;
        const int s = tid & 1;
        const int m = k * 257 + b;          // span start element (flat)
        const int o = (m >> 2) + s;         // affected float4 group
        const int e0 = o * 4;
        float vv[4];
        #pragma unroll
        for (int c = 0; c < 4; ++c) {
            const int d = e0 + c - m;       // offset into the 5-value span
            float v = 0.0f;
            v = (d == 0) ? v0 : v;
            v = (d == 1) ? v1 : v;
            v = (d == 2) ? v2 : v;
            v = (d == 3) ? v3 : v;
            v = (d == 4) ? v4 : v;
            vv[c] = v;
        }
        reg[o] = make_float4(vv[0], vv[1], vv[2], vv[3]);
    }

    // ---- pass B: zero-fill all non-affected groups ----
    const int sb3   = b - 3;     // skip iff r-b in [-3,4]  (row k overlap)
    const int sb254 = b + 254;   // skip iff r >= b+254      (row k+1 overlap)
    const float4 z = make_float4(0.0f, 0.0f, 0.0f, 0.0f);
    for (int o = tid; o < ROW4; o += 256) {
        const int e = o * 4;
        const int k = (e - (e >> 8)) >> 8;        // exact e/257 for e < 16448
        const int r = e - k * 257;                // column of first element
        const bool skip = ((unsigned)(r - sb3) < 8u) || (r >= sb254);
        if (!skip) reg[o] = z;
    }
}

// ---------------------------------------------------------------------------
// Fallback (ws too small): the R1 fused kernel, known-correct.
// ---------------------------------------------------------------------------
__global__ __launch_bounds__(256) void kann_fused_kernel(
    const float* __restrict__ x, const float* __restrict__ weight,
    float* __restrict__ out)
{
    const int i   = blockIdx.x;
    const int tid = threadIdx.x;

    __shared__ float s_b[15];
    __shared__ int   s_base;

    float xt;
    const int base = sample_base_xt(x[i], &xt);
    float phi[5], dphi[5], ddphi[5];
    basis_eval(xt, phi, dphi, ddphi);

    if (tid == 0) {
        #pragma unroll
        for (int j = 0; j < 5; ++j) {
            s_b[j] = phi[j]; s_b[5 + j] = dphi[j]; s_b[10 + j] = ddphi[j];
        }
        s_base = base;
    }

    float* t_out   = out;
    float* dt_out  = out + SW;
    float* ddt_out = out + 2 * (size_t)SW;
    float* big     = out + 3 * (size_t)SW;

    if (tid < NW) {
        const float* wrow = weight + tid * NNODES + base;
        float t = 0.0f, dt = 0.0f, ddt = 0.0f;
        #pragma unroll
        for (int j = 0; j < 5; ++j) {
            const float w = wrow[j];
            t += w * phi[j]; dt += w * dphi[j]; ddt += w * ddphi[j];
        }
        t_out[i * NW + tid] = t; dt_out[i * NW + tid] = dt; ddt_out[i * NW + tid] = ddt;
    }
    if (i == 0 && tid == 0) out[3 * (size_t)SW + 3 * SWN] = 0.0078125f;

    const float4 z = make_float4(0.0f, 0.0f, 0.0f, 0.0f);
    #pragma unroll
    for (int a = 0; a < 3; ++a) {
        float4* reg = reinterpret_cast<float4*>(big + (size_t)a * SWN + (size_t)i * ROW);
        for (int f4 = tid; f4 < ROW / 4; f4 += 256) reg[f4] = z;
    }
    __syncthreads();
    const int bb = s_base;
    #pragma unroll
    for (int a = 0; a < 3; ++a) {
        float* regp = big + (size_t)a * SWN + (size_t)i * ROW;
        for (int t = tid; t < NW * 5; t += 256) {
            const int k = t / 5;
            const int j = t - k * 5;
            regp[k * NNODES + bb + j] = s_b[a * 5 + j];
        }
    }
}

extern "C" void kernel_launch(void* const* d_in, const int* in_sizes, int n_in,
                              void* d_out, int out_size, void* d_ws, size_t ws_size,
                              hipStream_t stream) {
    const float* x      = (const float*)d_in[0];
    const float* weight = (const float*)d_in[1];
    float* out          = (float*)d_out;

    if (ws_size >= (size_t)NS * 16 * sizeof(float)) {
        float* ws = (float*)d_ws;
        k_basis<<<NS / 256, 256, 0, stream>>>(x, ws);
        dim3 g3(NS, 3);
        k_fill<<<g3, 256, 0, stream>>>(ws, out);
        k_dots<<<NS / 4, 256, 0, stream>>>(ws, weight, out);
    } else {
        kann_fused_kernel<<<NS, 256, 0, stream>>>(x, weight, out);
    }
}

// Round 4
// 164.690 us; speedup vs baseline: 1.5127x; 1.5127x over previous
//
#include <hip/hip_runtime.h>

// Problem constants (from reference)
#define NS     4096                 // N_SAMPLES
#define NW     64                   // N_WIDTH
#define NNODES 257                  // N_NODES
#define SW     (NS * NW)            // 262144
#define ROW    (NW * NNODES)        // 16448 floats per sample region
#define ROW4   (ROW / 4)            // 4112 float4 groups per sample region
#define SWN    ((size_t)NS * NW * NNODES)  // 67,371,008

// Hard-coded Lagrange basis polynomials over nodes [-1,-0.5,0,0.5,1].
// phi_j  : degree-4 Horner coefficients (x^4..x^0)
// dphi_j : derivative coeffs, pre-scaled by 1/delta_x   = 128
// ddphi_j: 2nd-deriv coeffs,  pre-scaled by 1/delta_x^2 = 16384
__device__ __constant__ const float P4[5] = { (float)( 2.0/3.0), (float)(-8.0/3.0),  4.0f, (float)(-8.0/3.0), (float)( 2.0/3.0) };
__device__ __constant__ const float P3[5] = { (float)(-2.0/3.0), (float)( 4.0/3.0),  0.0f, (float)(-4.0/3.0), (float)( 2.0/3.0) };
__device__ __constant__ const float P2[5] = { (float)(-1.0/6.0), (float)( 8.0/3.0), -5.0f, (float)( 8.0/3.0), (float)(-1.0/6.0) };
__device__ __constant__ const float P1[5] = { (float)( 1.0/6.0), (float)(-4.0/3.0),  0.0f, (float)( 4.0/3.0), (float)(-1.0/6.0) };
__device__ __constant__ const float P0[5] = { 0.0f, 0.0f, 1.0f, 0.0f, 0.0f };

__device__ __constant__ const float D3[5] = { (float)( 1024.0/3.0), (float)(-4096.0/3.0),  2048.0f, (float)(-4096.0/3.0), (float)(1024.0/3.0) };
__device__ __constant__ const float D2[5] = { -256.0f, 512.0f, 0.0f, -512.0f, 256.0f };
__device__ __constant__ const float D1[5] = { (float)( -128.0/3.0), (float)( 2048.0/3.0), -1280.0f, (float)( 2048.0/3.0), (float)(-128.0/3.0) };
__device__ __constant__ const float D0[5] = { (float)(   64.0/3.0), (float)( -512.0/3.0),     0.0f, (float)(  512.0/3.0), (float)( -64.0/3.0) };

// L''(x)*16384:  L3'' = -32x^2 - 8x + 16/3  ->  E1[3] = -131072  (R3 bug: was +)
__device__ __constant__ const float E2[5] = { 131072.0f, -524288.0f, 786432.0f, -524288.0f, 131072.0f };
__device__ __constant__ const float E1[5] = { -65536.0f,  131072.0f,      0.0f, -131072.0f,  65536.0f };
__device__ __constant__ const float E0[5] = { (float)(-16384.0/3.0), (float)(262144.0/3.0), -163840.0f, (float)(262144.0/3.0), (float)(-16384.0/3.0) };

__global__ __launch_bounds__(256) void kann_all(
    const float* __restrict__ x,
    const float* __restrict__ weight,   // [64, 257]
    float* __restrict__ out)
{
    const int i   = blockIdx.x;       // sample
    const int tid = threadIdx.x;

    __shared__ __align__(16) float tmpl[3][1028];   // row template, period 257, x4 for f4 alignment

    // ---- per-sample basis (Horner, no divides; redundant per thread) ----
    const float xs = 256.0f * x[i];
    float fel = floorf(xs * 0.25f);
    fel = fminf(fmaxf(fel, 0.0f), 63.0f);
    const int   b = (int)fel * 4;                    // first affected node
    const float t = 0.5f * (xs - (float)b) - 1.0f;   // reference coord in [-1,1]

    float bas[3][5];
    #pragma unroll
    for (int j = 0; j < 5; ++j) {
        bas[0][j] = (((P4[j]*t + P3[j])*t + P2[j])*t + P1[j])*t + P0[j];
        bas[1][j] = ((D3[j]*t + D2[j])*t + D1[j])*t + D0[j];
        bas[2][j] = (E2[j]*t + E1[j])*t + E0[j];
    }

    // ---- t/dt/ddt dot products (threads 0..63, before barrier) ----
    if (tid < NW) {
        const float* wrow = weight + tid * NNODES + b;
        float s0 = 0.0f, s1 = 0.0f, s2 = 0.0f;
        #pragma unroll
        for (int j = 0; j < 5; ++j) {
            const float w = wrow[j];
            s0 += w * bas[0][j];
            s1 += w * bas[1][j];
            s2 += w * bas[2][j];
        }
        out[(size_t)i * NW + tid]               = s0;
        out[SW + (size_t)i * NW + tid]          = s1;
        out[2 * (size_t)SW + (size_t)i * NW + tid] = s2;
    }
    if (i == 0 && tid == 64)
        out[3 * (size_t)SW + 3 * SWN] = 0.0078125f;  // delta_x

    // ---- build LDS row template: tmpl[a][idx] = row_a[idx mod 257] ----
    #pragma unroll
    for (int a = 0; a < 3; ++a) {
        for (int idx = tid; idx < 1028; idx += 256) {
            const int q = (idx - (idx >> 8)) >> 8;   // idx / 257 (exact for idx < 65792)
            const int r = idx - ((q << 8) + q);      // idx mod 257
            const int d = r - b;
            float v = 0.0f;
            v = (d == 0) ? bas[a][0] : v;
            v = (d == 1) ? bas[a][1] : v;
            v = (d == 2) ? bas[a][2] : v;
            v = (d == 3) ? bas[a][3] : v;
            v = (d == 4) ? bas[a][4] : v;
            tmpl[a][idx] = v;
        }
    }
    __syncthreads();   // ds_writes visible; no global stores pending from fill yet

    // ---- single-pass streaming fill: every group written exactly once ----
    float* big = out + 3 * (size_t)SW + (size_t)i * ROW;
    #pragma unroll
    for (int a = 0; a < 3; ++a) {
        float4* reg = reinterpret_cast<float4*>(big + (size_t)a * SWN);
        const float4* t4 = reinterpret_cast<const float4*>(tmpl[a]);
        #pragma unroll 4
        for (int o = tid; o < ROW4; o += 256) {
            const int q  = (o - (o >> 8)) >> 8;      // o / 257
            const int om = o - ((q << 8) + q);       // o mod 257
            reg[o] = t4[om];                          // ds_read_b128 + store_dwordx4
        }
    }
}

extern "C" void kernel_launch(void* const* d_in, const int* in_sizes, int n_in,
                              void* d_out, int out_size, void* d_ws, size_t ws_size,
                              hipStream_t stream) {
    const float* x      = (const float*)d_in[0];
    const float* weight = (const float*)d_in[1];
    float* out          = (float*)d_out;
    kann_all<<<NS, 256, 0, stream>>>(x, weight, out);
}